// Round 4
// baseline (296.496 us; speedup 1.0000x reference)
//
#include <hip/hip_runtime.h>
#include <math.h>

#define NWIN  4096
#define NHIST 7168                   // 7*1024; float bins (counts exact < 2^24)
#define SEGW  (3*NWIN)               // [sum_p | sum_pr | sum_pd]
#define CE_OFF (SEGW + NHIST)        // 19456: 8 wnll + 8 w partials
#define CW    (CE_OFF + 16)          // 19472 words per copy
#define CWP   19520                  // padded stride = 305*64 words (78080 B)
#define MAXBLK 512

#define SERVICE    1.0e8f   // CAPACITY * DELTA_T
#define CAPACITY_F 1.0e9f
#define DELTA_T_F  0.1f

// per-row work, shared by all paths
__device__ __forceinline__
void row_op(float l0, float l1, int yy, int mk, int wi,
            float dob_raw, float pr_raw, float as_raw,
            float cw0, float cw1, float* lds, float& awn, float& aw)
{
    float d = l0 - l1;
    float e = __expf(d);
    float t = __logf(1.0f + e);
    float nll = yy ? t : (t - d);
    float w   = (yy ? cw1 : cw0) * (mk ? 1.0f : 0.0f);
    awn += w * nll;
    aw  += w;
    if (mk && wi >= 0) {
        float p   = 1.0f / (1.0f + e);
        int   seg = (wi < NWIN) ? wi : (NWIN - 1);
        float dob = fmaxf(dob_raw, 0.0f);
        float pr  = fmaxf(pr_raw,  0.0f);
        float as  = fmaxf(as_raw,  0.0f) * 1000.0f;
        unsafeAtomicAdd(&lds[seg],            p);
        unsafeAtomicAdd(&lds[NWIN + seg],     p * (pr * as));
        unsafeAtomicAdd(&lds[2 * NWIN + seg], p * dob);
        int b = (int)(dob * (float)NHIST);
        b = (b < NHIST - 1) ? b : (NHIST - 1);
        b = (b > 0) ? b : 0;
        unsafeAtomicAdd(&lds[SEGW + b], 1.0f);
    }
}

// ---------------- K1: one pass over all rows, 4-row batched loads ----------------
// MODE 1: plain stores to private copy. MODE 0: atomic fallback into fin at ws[0].
template<int MODE>
__global__ __launch_bounds__(512, 4)
void pl_k1(const float* __restrict__ logits, const int* __restrict__ y,
           const int* __restrict__ mask, const float* __restrict__ x_raw,
           const int* __restrict__ widx, const float* __restrict__ cw,
           float* __restrict__ ws, int n)
{
    __shared__ float lds[SEGW + NHIST];   // 77824 B -> 2 blocks/CU
    __shared__ float ce[2][8];
    const int tid = threadIdx.x;
    for (int s = tid; s < SEGW + NHIST; s += 512) lds[s] = 0.0f;
    __syncthreads();

    const float cw0 = cw[0], cw1 = cw[1];
    float awn = 0.0f, aw = 0.0f;

    const int gid     = blockIdx.x * 512 + tid;
    const int stride  = gridDim.x * 512;
    const int ngroups = n >> 2;

    for (int g = gid; g < ngroups; g += stride) {
        // ---- issue ALL loads for 4 rows up front (independent, wide) ----
        float4 lgA = ((const float4*)logits)[2 * (size_t)g];      // rows 4g,4g+1
        float4 lgB = ((const float4*)logits)[2 * (size_t)g + 1];  // rows 4g+2,4g+3
        int4   yy  = ((const int4*)y)[g];
        int4   mk  = ((const int4*)mask)[g];
        int4   wi  = ((const int4*)widx)[g];
        const float* xr = x_raw + 32 * (size_t)g;   // 4 rows x 8 cols
        float2 xa0 = *(const float2*)(xr + 2);   float xb0 = xr[4];
        float2 xa1 = *(const float2*)(xr + 10);  float xb1 = xr[12];
        float2 xa2 = *(const float2*)(xr + 18);  float xb2 = xr[20];
        float2 xa3 = *(const float2*)(xr + 26);  float xb3 = xr[28];

        row_op(lgA.x, lgA.y, yy.x, mk.x, wi.x, xa0.x, xa0.y, xb0, cw0, cw1, lds, awn, aw);
        row_op(lgA.z, lgA.w, yy.y, mk.y, wi.y, xa1.x, xa1.y, xb1, cw0, cw1, lds, awn, aw);
        row_op(lgB.x, lgB.y, yy.z, mk.z, wi.z, xa2.x, xa2.y, xb2, cw0, cw1, lds, awn, aw);
        row_op(lgB.z, lgB.w, yy.w, mk.w, wi.w, xa3.x, xa3.y, xb3, cw0, cw1, lds, awn, aw);
    }

    // tail rows (n not divisible by 4) — zero-trip for N=4M
    for (int i = (ngroups << 2) + gid; i < n; i += stride) {
        float2 lg = ((const float2*)logits)[i];
        row_op(lg.x, lg.y, y[i], mask[i], widx[i],
               x_raw[8*(size_t)i+2], x_raw[8*(size_t)i+3], x_raw[8*(size_t)i+4],
               cw0, cw1, lds, awn, aw);
    }

    for (int o = 32; o > 0; o >>= 1) {
        awn += __shfl_down(awn, o, 64);
        aw  += __shfl_down(aw,  o, 64);
    }
    if ((tid & 63) == 0) { ce[0][tid >> 6] = awn; ce[1][tid >> 6] = aw; }
    __syncthreads();

    if (MODE == 1) {
        float* cb = ws + (size_t)blockIdx.x * CWP;
        for (int s = tid; s < SEGW + NHIST; s += 512) cb[s] = lds[s];
        if (tid < 8)       cb[CE_OFF + tid]     = ce[0][tid];
        else if (tid < 16) cb[CE_OFF + tid]     = ce[1][tid - 8];
    } else {
        for (int s = tid; s < SEGW + NHIST; s += 512)
            if (lds[s] != 0.0f) unsafeAtomicAdd(&ws[s], lds[s]);
        if (tid < 8)       unsafeAtomicAdd(&ws[CE_OFF + tid], ce[0][tid]);
        else if (tid < 16) unsafeAtomicAdd(&ws[CE_OFF + tid], ce[1][tid - 8]);
    }
}

// ---------------- Kmid: reduce C private copies into fin ----------------
__global__ __launch_bounds__(256)
void pl_kmid(const float* __restrict__ ws, float* __restrict__ fin, int C)
{
    __shared__ float sRed[256];
    const int j   = threadIdx.x & 63;
    const int g   = threadIdx.x >> 6;
    const int idx = blockIdx.x * 64 + j;

    float a0 = 0.f, a1 = 0.f, a2 = 0.f, a3 = 0.f;
    if (idx < CW) {
        int c = g;
        for (; c + 12 < C; c += 16) {
            a0 += ws[(size_t)(c)      * CWP + idx];
            a1 += ws[(size_t)(c + 4)  * CWP + idx];
            a2 += ws[(size_t)(c + 8)  * CWP + idx];
            a3 += ws[(size_t)(c + 12) * CWP + idx];
        }
        for (; c < C; c += 4) a0 += ws[(size_t)c * CWP + idx];
    }
    sRed[threadIdx.x] = (a0 + a1) + (a2 + a3);
    __syncthreads();
    if (g == 0 && idx < CW)
        fin[idx] = (sRed[j] + sRed[64 + j]) + (sRed[128 + j] + sRed[192 + j]);
}

// ---------------- K2: quantile + parallel window scan + outputs ----------------
__global__ __launch_bounds__(1024)
void pl_k2(const float* __restrict__ fin, float* __restrict__ out)
{
    __shared__ float        sS[1024];
    __shared__ float        sM[1024];
    __shared__ unsigned int sC[1024];
    __shared__ float        sV[2];
    __shared__ float        sRed[3][16];

    const int tid = threadIdx.x;
    const float* hist = fin + SEGW;
    const int CHUNK = NHIST / 1024;   // 7 bins per thread

    unsigned int hv[CHUNK];
    unsigned int c = 0;
    const int base = tid * CHUNK;
    for (int j = 0; j < CHUNK; ++j) { hv[j] = (unsigned int)hist[base + j]; c += hv[j]; }
    sC[tid] = c;
    __syncthreads();
    for (int off = 1; off < 1024; off <<= 1) {
        unsigned int v = (tid >= off) ? sC[tid - off] : 0u;
        __syncthreads();
        sC[tid] += v;
        __syncthreads();
    }
    const unsigned int nv  = sC[1023];
    const unsigned int pre = sC[tid] - c;

    if (tid == 0) { sV[0] = 1.0f; sV[1] = 1.0f; }
    __syncthreads();

    float nvf  = (float)nv;
    float pos  = 0.75f * (nvf - 1.0f);
    float fpos = floorf(pos);
    long  lo_l = (long)fpos;
    long  hi_l = (long)ceilf(pos);
    long  nmax = (nv > 0) ? (long)nv - 1 : 0;
    lo_l = lo_l < 0 ? 0 : (lo_l > nmax ? nmax : lo_l);
    hi_l = hi_l < 0 ? 0 : (hi_l > nmax ? nmax : hi_l);
    float frac = pos - fpos;

    if (nv > 0) {
        unsigned int lo = (unsigned int)lo_l, hi = (unsigned int)hi_l;
        if (lo >= pre && lo < pre + c) {
            unsigned int acc = pre;
            for (int j = 0; j < CHUNK; ++j) {
                acc += hv[j];
                if (lo < acc) { sV[0] = ((float)(base + j) + 0.5f) * (1.0f / (float)NHIST); break; }
            }
        }
        if (hi >= pre && hi < pre + c) {
            unsigned int acc = pre;
            for (int j = 0; j < CHUNK; ++j) {
                acc += hv[j];
                if (hi < acc) { sV[1] = ((float)(base + j) + 0.5f) * (1.0f / (float)NHIST); break; }
            }
        }
    }
    __syncthreads();
    float ref      = sV[0] * (1.0f - frac) + sV[1] * frac;
    float ref_dobs = fmaxf(ref, 1e-6f);
    float inv_ref  = 1.0f / ref_dobs;

    const float* f_sp  = fin;
    const float* f_spr = fin + NWIN;
    const float* f_spd = fin + 2 * NWIN;

    float va[4], vsp[4], vspr[4], vspd[4];
    bool  vinc[4];
    float S = 0.0f, M = -3.0e38f;
    const int w0 = tid * 4;
    for (int j = 0; j < 4; ++j) {
        int   wdx = w0 + j;
        float sp  = f_sp[wdx];
        float spr = f_spr[wdx];
        float spd = f_spd[wdx];
        float a   = spr * DELTA_T_F - SERVICE;
        bool  inc = (sp >= 1e-8f);   // == (cnt>=1 && sp>=1e-8)
        va[j] = a; vsp[j] = sp; vspr[j] = spr; vspd[j] = spd; vinc[j] = inc;
        if (inc) { M = fmaxf(M + a, 0.0f); S = S + a; }
    }
    sS[tid] = S; sM[tid] = M;
    __syncthreads();
    for (int off = 1; off < 1024; off <<= 1) {
        float vs = 0.0f, vm = -3.0e38f;
        if (tid >= off) { vs = sS[tid - off]; vm = sM[tid - off]; }
        __syncthreads();
        if (tid >= off) {
            float s2 = sS[tid], m2 = sM[tid];
            sS[tid] = vs + s2;
            sM[tid] = fmaxf(vm + s2, m2);
        }
        __syncthreads();
    }
    float q = 0.0f;
    if (tid > 0) q = fmaxf(sS[tid - 1], sM[tid - 1]);

    float fsum = 0.0f, lsum = 0.0f, isum = 0.0f;
    for (int j = 0; j < 4; ++j) {
        float qn    = fmaxf(q + va[j], 0.0f);
        float dmean = vspd[j] / (vsp[j] + 1e-6f);
        float dsc   = dmean * inv_ref;
        float oq    = fmaxf(dsc - 1.0f, 0.0f) * SERVICE;
        float fw    = (qn - oq) / (SERVICE + 1e-6f);
        fw = fw * fw;
        float rho = vspr[j] / (CAPACITY_F + 1e-6f);
        rho = fminf(fmaxf(rho, 0.0f), 0.995f);
        float dth = 1.0f / (1.0f - rho + 1e-6f);
        float lt  = fmaxf(dth - dsc, 0.0f);
        if (vinc[j]) { fsum += fw; lsum += lt; isum += 1.0f; q = qn; }
    }

    for (int o = 32; o > 0; o >>= 1) {
        fsum += __shfl_down(fsum, o, 64);
        lsum += __shfl_down(lsum, o, 64);
        isum += __shfl_down(isum, o, 64);
    }
    const int wv = tid >> 6;
    if ((tid & 63) == 0) { sRed[0][wv] = fsum; sRed[1][wv] = lsum; sRed[2][wv] = isum; }
    __syncthreads();
    if (tid == 0) {
        float F = 0.0f, L = 0.0f, I = 0.0f;
        float A = 0.0f, B = 0.0f;
        for (int k = 0; k < 16; ++k) { F += sRed[0][k]; L += sRed[1][k]; I += sRed[2][k]; }
        for (int k = 0; k < 8; ++k)  { A += fin[CE_OFF + k]; B += fin[CE_OFF + 8 + k]; }
        float l_data = A / B;
        float l_flow = (I > 0.0f) ? F / fmaxf(I, 1.0f) : 0.0f;
        float l_lat  = (I > 0.0f) ? L / fmaxf(I, 1.0f) : 0.0f;
        out[0] = l_data + 0.1f * l_flow + 0.1f * l_lat;
        out[1] = l_data;
        out[2] = l_flow;
        out[3] = l_lat;
    }
}

extern "C" void kernel_launch(void* const* d_in, const int* in_sizes, int n_in,
                              void* d_out, int out_size, void* d_ws, size_t ws_size,
                              hipStream_t stream) {
    const float* logits = (const float*)d_in[0];
    const int*   y      = (const int*)d_in[1];
    const int*   mask   = (const int*)d_in[2];
    const float* x_raw  = (const float*)d_in[3];
    const int*   widx   = (const int*)d_in[4];
    const float* cw     = (const float*)d_in[5];
    float* out = (float*)d_out;
    int n = in_sizes[1];   // N from y

    float* ws = (float*)d_ws;
    size_t words = ws_size / 4;
    long   cap   = (words > CW) ? (long)((words - CW) / CWP) : 0;
    int    nblk  = (cap > MAXBLK) ? MAXBLK : (int)cap;

    if (nblk >= 64) {
        float* fin = ws + (size_t)nblk * CWP;
        hipLaunchKernelGGL((pl_k1<1>), dim3(nblk), dim3(512), 0, stream,
                           logits, y, mask, x_raw, widx, cw, ws, n);
        hipLaunchKernelGGL(pl_kmid, dim3((CW + 63) / 64), dim3(256), 0, stream,
                           ws, fin, nblk);
        hipLaunchKernelGGL(pl_k2, dim3(1), dim3(1024), 0, stream,
                           fin, out);
    } else {
        hipMemsetAsync(d_ws, 0, (size_t)CW * 4, stream);
        hipLaunchKernelGGL((pl_k1<0>), dim3(512), dim3(512), 0, stream,
                           logits, y, mask, x_raw, widx, cw, ws, n);
        hipLaunchKernelGGL(pl_k2, dim3(1), dim3(1024), 0, stream,
                           ws, out);
    }
}

// Round 5
// 284.920 us; speedup vs baseline: 1.0406x; 1.0406x over previous
//
#include <hip/hip_runtime.h>
#include <math.h>

#define NWIN  4096
#define NHIST 7168                   // 7*1024; float bins (counts exact < 2^24)
#define SEGW  (3*NWIN)               // [sum_p | sum_pr | sum_pd]
#define CE_OFF (SEGW + NHIST)        // 19456: 16 wnll + 16 w partials
#define CW    (CE_OFF + 32)          // 19488 words per copy
#define CWP   19520                  // padded stride = 305*64 words (78080 B)
#define MAXBLK 512

#define SERVICE    1.0e8f   // CAPACITY * DELTA_T
#define CAPACITY_F 1.0e9f
#define DELTA_T_F  0.1f

// per-row work, shared by all paths
__device__ __forceinline__
void row_op(float l0, float l1, int yy, int mk, int wi,
            float dob_raw, float pr_raw, float as_raw,
            float cw0, float cw1, float* lds, float& awn, float& aw)
{
    float d = l0 - l1;
    float e = __expf(d);
    float t = __logf(1.0f + e);
    float nll = yy ? t : (t - d);
    float w   = (yy ? cw1 : cw0) * (mk ? 1.0f : 0.0f);
    awn += w * nll;
    aw  += w;
    if (mk && wi >= 0) {
        float p   = 1.0f / (1.0f + e);
        int   seg = (wi < NWIN) ? wi : (NWIN - 1);
        float dob = fmaxf(dob_raw, 0.0f);
        float pr  = fmaxf(pr_raw,  0.0f);
        float as  = fmaxf(as_raw,  0.0f) * 1000.0f;
        unsafeAtomicAdd(&lds[seg],            p);
        unsafeAtomicAdd(&lds[NWIN + seg],     p * (pr * as));
        unsafeAtomicAdd(&lds[2 * NWIN + seg], p * dob);
        int b = (int)(dob * (float)NHIST);
        b = (b < NHIST - 1) ? b : (NHIST - 1);
        b = (b > 0) ? b : 0;
        unsafeAtomicAdd(&lds[SEGW + b], 1.0f);
    }
}

// ---------------- K1: wave-contiguous streaming, 2 rows/lane (one 64B x_raw line) ----------------
// MODE 1: plain stores to private copy. MODE 0: atomic fallback into fin at ws[0].
template<int MODE>
__global__ __launch_bounds__(1024, 8)
void pl_k1(const float* __restrict__ logits, const int* __restrict__ y,
           const int* __restrict__ mask, const float* __restrict__ x_raw,
           const int* __restrict__ widx, const float* __restrict__ cw,
           float* __restrict__ ws, int n)
{
    __shared__ float lds[SEGW + NHIST];   // 77824 B -> 2 blocks/CU (32 waves)
    __shared__ float ce[2][16];
    const int tid = threadIdx.x;
    for (int s = tid; s < SEGW + NHIST; s += 1024) lds[s] = 0.0f;
    __syncthreads();

    const float cw0 = cw[0], cw1 = cw[1];
    float awn = 0.0f, aw = 0.0f;

    const int lane    = tid & 63;
    const int wave    = blockIdx.x * 16 + (tid >> 6);
    const int nwaves  = gridDim.x * 16;
    const int ngroups = (n + 127) >> 7;                 // groups of 128 rows
    const int gpw     = (ngroups + nwaves - 1) / nwaves;
    const int g0      = wave * gpw;
    int       g1      = g0 + gpw; if (g1 > ngroups) g1 = ngroups;

    for (int g = g0; g < g1; ++g) {
        const int r0 = (g << 7) + (lane << 1);          // rows r0, r0+1 (contiguous per wave)
        if (r0 >= n) break;
        if (r0 + 1 < n) {
            // all loads independent, issued up front; x_raw pair shares one 64B line
            float4 lg = ((const float4*)logits)[r0 >> 1];
            int2   yy = ((const int2*)y)[r0 >> 1];
            int2   mk = ((const int2*)mask)[r0 >> 1];
            int2   wi = ((const int2*)widx)[r0 >> 1];
            const float* xr = x_raw + 8 * (size_t)r0;
            float2 a0 = *(const float2*)(xr + 2);       // r0   cols 2,3
            float2 b0 = *(const float2*)(xr + 4);       // r0   cols 4,5
            float2 a1 = *(const float2*)(xr + 10);      // r0+1 cols 2,3
            float2 b1 = *(const float2*)(xr + 12);      // r0+1 cols 4,5

            row_op(lg.x, lg.y, yy.x, mk.x, wi.x, a0.x, a0.y, b0.x, cw0, cw1, lds, awn, aw);
            row_op(lg.z, lg.w, yy.y, mk.y, wi.y, a1.x, a1.y, b1.x, cw0, cw1, lds, awn, aw);
        } else {
            float2 lg = ((const float2*)logits)[r0];
            row_op(lg.x, lg.y, y[r0], mask[r0], widx[r0],
                   x_raw[8*(size_t)r0+2], x_raw[8*(size_t)r0+3], x_raw[8*(size_t)r0+4],
                   cw0, cw1, lds, awn, aw);
        }
    }

    for (int o = 32; o > 0; o >>= 1) {
        awn += __shfl_down(awn, o, 64);
        aw  += __shfl_down(aw,  o, 64);
    }
    if ((tid & 63) == 0) { ce[0][tid >> 6] = awn; ce[1][tid >> 6] = aw; }
    __syncthreads();

    if (MODE == 1) {
        float* cb = ws + (size_t)blockIdx.x * CWP;
        for (int s = tid; s < SEGW + NHIST; s += 1024) cb[s] = lds[s];
        if (tid < 16)      cb[CE_OFF + tid]      = ce[0][tid];
        else if (tid < 32) cb[CE_OFF + tid]      = ce[1][tid - 16];
    } else {
        for (int s = tid; s < SEGW + NHIST; s += 1024)
            if (lds[s] != 0.0f) unsafeAtomicAdd(&ws[s], lds[s]);
        if (tid < 16)      unsafeAtomicAdd(&ws[CE_OFF + tid], ce[0][tid]);
        else if (tid < 32) unsafeAtomicAdd(&ws[CE_OFF + tid], ce[1][tid - 16]);
    }
}

// ---------------- Kmid: reduce C private copies into fin ----------------
__global__ __launch_bounds__(256)
void pl_kmid(const float* __restrict__ ws, float* __restrict__ fin, int C)
{
    __shared__ float sRed[256];
    const int j   = threadIdx.x & 63;
    const int g   = threadIdx.x >> 6;
    const int idx = blockIdx.x * 64 + j;

    float a0 = 0.f, a1 = 0.f, a2 = 0.f, a3 = 0.f;
    if (idx < CW) {
        int c = g;
        for (; c + 12 < C; c += 16) {
            a0 += ws[(size_t)(c)      * CWP + idx];
            a1 += ws[(size_t)(c + 4)  * CWP + idx];
            a2 += ws[(size_t)(c + 8)  * CWP + idx];
            a3 += ws[(size_t)(c + 12) * CWP + idx];
        }
        for (; c < C; c += 4) a0 += ws[(size_t)c * CWP + idx];
    }
    sRed[threadIdx.x] = (a0 + a1) + (a2 + a3);
    __syncthreads();
    if (g == 0 && idx < CW)
        fin[idx] = (sRed[j] + sRed[64 + j]) + (sRed[128 + j] + sRed[192 + j]);
}

// ---------------- K2: quantile + parallel window scan + outputs ----------------
__global__ __launch_bounds__(1024)
void pl_k2(const float* __restrict__ fin, float* __restrict__ out)
{
    __shared__ float        sS[1024];
    __shared__ float        sM[1024];
    __shared__ unsigned int sC[1024];
    __shared__ float        sV[2];
    __shared__ float        sRed[3][16];

    const int tid = threadIdx.x;
    const float* hist = fin + SEGW;
    const int CHUNK = NHIST / 1024;   // 7 bins per thread

    unsigned int hv[CHUNK];
    unsigned int c = 0;
    const int base = tid * CHUNK;
    for (int j = 0; j < CHUNK; ++j) { hv[j] = (unsigned int)hist[base + j]; c += hv[j]; }
    sC[tid] = c;
    __syncthreads();
    for (int off = 1; off < 1024; off <<= 1) {
        unsigned int v = (tid >= off) ? sC[tid - off] : 0u;
        __syncthreads();
        sC[tid] += v;
        __syncthreads();
    }
    const unsigned int nv  = sC[1023];
    const unsigned int pre = sC[tid] - c;

    if (tid == 0) { sV[0] = 1.0f; sV[1] = 1.0f; }
    __syncthreads();

    float nvf  = (float)nv;
    float pos  = 0.75f * (nvf - 1.0f);
    float fpos = floorf(pos);
    long  lo_l = (long)fpos;
    long  hi_l = (long)ceilf(pos);
    long  nmax = (nv > 0) ? (long)nv - 1 : 0;
    lo_l = lo_l < 0 ? 0 : (lo_l > nmax ? nmax : lo_l);
    hi_l = hi_l < 0 ? 0 : (hi_l > nmax ? nmax : hi_l);
    float frac = pos - fpos;

    if (nv > 0) {
        unsigned int lo = (unsigned int)lo_l, hi = (unsigned int)hi_l;
        if (lo >= pre && lo < pre + c) {
            unsigned int acc = pre;
            for (int j = 0; j < CHUNK; ++j) {
                acc += hv[j];
                if (lo < acc) { sV[0] = ((float)(base + j) + 0.5f) * (1.0f / (float)NHIST); break; }
            }
        }
        if (hi >= pre && hi < pre + c) {
            unsigned int acc = pre;
            for (int j = 0; j < CHUNK; ++j) {
                acc += hv[j];
                if (hi < acc) { sV[1] = ((float)(base + j) + 0.5f) * (1.0f / (float)NHIST); break; }
            }
        }
    }
    __syncthreads();
    float ref      = sV[0] * (1.0f - frac) + sV[1] * frac;
    float ref_dobs = fmaxf(ref, 1e-6f);
    float inv_ref  = 1.0f / ref_dobs;

    const float* f_sp  = fin;
    const float* f_spr = fin + NWIN;
    const float* f_spd = fin + 2 * NWIN;

    float va[4], vsp[4], vspr[4], vspd[4];
    bool  vinc[4];
    float S = 0.0f, M = -3.0e38f;
    const int w0 = tid * 4;
    for (int j = 0; j < 4; ++j) {
        int   wdx = w0 + j;
        float sp  = f_sp[wdx];
        float spr = f_spr[wdx];
        float spd = f_spd[wdx];
        float a   = spr * DELTA_T_F - SERVICE;
        bool  inc = (sp >= 1e-8f);   // == (cnt>=1 && sp>=1e-8)
        va[j] = a; vsp[j] = sp; vspr[j] = spr; vspd[j] = spd; vinc[j] = inc;
        if (inc) { M = fmaxf(M + a, 0.0f); S = S + a; }
    }
    sS[tid] = S; sM[tid] = M;
    __syncthreads();
    for (int off = 1; off < 1024; off <<= 1) {
        float vs = 0.0f, vm = -3.0e38f;
        if (tid >= off) { vs = sS[tid - off]; vm = sM[tid - off]; }
        __syncthreads();
        if (tid >= off) {
            float s2 = sS[tid], m2 = sM[tid];
            sS[tid] = vs + s2;
            sM[tid] = fmaxf(vm + s2, m2);
        }
        __syncthreads();
    }
    float q = 0.0f;
    if (tid > 0) q = fmaxf(sS[tid - 1], sM[tid - 1]);

    float fsum = 0.0f, lsum = 0.0f, isum = 0.0f;
    for (int j = 0; j < 4; ++j) {
        float qn    = fmaxf(q + va[j], 0.0f);
        float dmean = vspd[j] / (vsp[j] + 1e-6f);
        float dsc   = dmean * inv_ref;
        float oq    = fmaxf(dsc - 1.0f, 0.0f) * SERVICE;
        float fw    = (qn - oq) / (SERVICE + 1e-6f);
        fw = fw * fw;
        float rho = vspr[j] / (CAPACITY_F + 1e-6f);
        rho = fminf(fmaxf(rho, 0.0f), 0.995f);
        float dth = 1.0f / (1.0f - rho + 1e-6f);
        float lt  = fmaxf(dth - dsc, 0.0f);
        if (vinc[j]) { fsum += fw; lsum += lt; isum += 1.0f; q = qn; }
    }

    for (int o = 32; o > 0; o >>= 1) {
        fsum += __shfl_down(fsum, o, 64);
        lsum += __shfl_down(lsum, o, 64);
        isum += __shfl_down(isum, o, 64);
    }
    const int wv = tid >> 6;
    if ((tid & 63) == 0) { sRed[0][wv] = fsum; sRed[1][wv] = lsum; sRed[2][wv] = isum; }
    __syncthreads();
    if (tid == 0) {
        float F = 0.0f, L = 0.0f, I = 0.0f;
        float A = 0.0f, B = 0.0f;
        for (int k = 0; k < 16; ++k) {
            F += sRed[0][k]; L += sRed[1][k]; I += sRed[2][k];
            A += fin[CE_OFF + k]; B += fin[CE_OFF + 16 + k];
        }
        float l_data = A / B;
        float l_flow = (I > 0.0f) ? F / fmaxf(I, 1.0f) : 0.0f;
        float l_lat  = (I > 0.0f) ? L / fmaxf(I, 1.0f) : 0.0f;
        out[0] = l_data + 0.1f * l_flow + 0.1f * l_lat;
        out[1] = l_data;
        out[2] = l_flow;
        out[3] = l_lat;
    }
}

extern "C" void kernel_launch(void* const* d_in, const int* in_sizes, int n_in,
                              void* d_out, int out_size, void* d_ws, size_t ws_size,
                              hipStream_t stream) {
    const float* logits = (const float*)d_in[0];
    const int*   y      = (const int*)d_in[1];
    const int*   mask   = (const int*)d_in[2];
    const float* x_raw  = (const float*)d_in[3];
    const int*   widx   = (const int*)d_in[4];
    const float* cw     = (const float*)d_in[5];
    float* out = (float*)d_out;
    int n = in_sizes[1];   // N from y

    float* ws = (float*)d_ws;
    size_t words = ws_size / 4;
    long   cap   = (words > CW) ? (long)((words - CW) / CWP) : 0;
    int    nblk  = (cap > MAXBLK) ? MAXBLK : (int)cap;

    if (nblk >= 64) {
        float* fin = ws + (size_t)nblk * CWP;
        hipLaunchKernelGGL((pl_k1<1>), dim3(nblk), dim3(1024), 0, stream,
                           logits, y, mask, x_raw, widx, cw, ws, n);
        hipLaunchKernelGGL(pl_kmid, dim3((CW + 63) / 64), dim3(256), 0, stream,
                           ws, fin, nblk);
        hipLaunchKernelGGL(pl_k2, dim3(1), dim3(1024), 0, stream,
                           fin, out);
    } else {
        hipMemsetAsync(d_ws, 0, (size_t)CW * 4, stream);
        hipLaunchKernelGGL((pl_k1<0>), dim3(512), dim3(1024), 0, stream,
                           logits, y, mask, x_raw, widx, cw, ws, n);
        hipLaunchKernelGGL(pl_k2, dim3(1), dim3(1024), 0, stream,
                           ws, out);
    }
}

// Round 6
// 283.642 us; speedup vs baseline: 1.0453x; 1.0045x over previous
//
#include <hip/hip_runtime.h>
#include <math.h>

#define NWIN  4096
#define NHIST 7168                   // 7*1024; float bins (counts exact < 2^24)
#define SEGW  (3*NWIN)               // [sum_p | sum_pr | sum_pd]
#define CE_OFF (SEGW + NHIST)        // 19456: 16 wnll + 16 w partials
#define CW    (CE_OFF + 32)          // 19488 words per copy
#define CWP   19520                  // padded stride = 305*64 words (78080 B)
#define MAXBLK 512

#define SERVICE    1.0e8f   // CAPACITY * DELTA_T
#define CAPACITY_F 1.0e9f
#define DELTA_T_F  0.1f

// per-row work, shared by all paths
__device__ __forceinline__
void row_op(float l0, float l1, int yy, int mk, int wi,
            float dob_raw, float pr_raw, float as_raw,
            float cw0, float cw1, float* lds, float& awn, float& aw)
{
    float d = l0 - l1;
    float e = __expf(d);
    float t = __logf(1.0f + e);
    float nll = yy ? t : (t - d);
    float w   = (yy ? cw1 : cw0) * (mk ? 1.0f : 0.0f);
    awn += w * nll;
    aw  += w;
    if (mk && wi >= 0) {
        float p   = 1.0f / (1.0f + e);
        int   seg = (wi < NWIN) ? wi : (NWIN - 1);
        float dob = fmaxf(dob_raw, 0.0f);
        float pr  = fmaxf(pr_raw,  0.0f);
        float as  = fmaxf(as_raw,  0.0f) * 1000.0f;
        unsafeAtomicAdd(&lds[seg],            p);
        unsafeAtomicAdd(&lds[NWIN + seg],     p * (pr * as));
        unsafeAtomicAdd(&lds[2 * NWIN + seg], p * dob);
        int b = (int)(dob * (float)NHIST);
        b = (b < NHIST - 1) ? b : (NHIST - 1);
        b = (b > 0) ? b : 0;
        unsafeAtomicAdd(&lds[SEGW + b], 1.0f);
    }
}

// ---------------- K1: ALL loads lane-consecutive dense; x_raw via shuffle transpose ----------------
// Per 64-row group: wave loads the group's x_raw span (2 KB) as 2 dense float4/lane,
// then ds_bpermute redistributes cols 2,3,4 to the owning lane. No extra LDS, no barriers.
// MODE 1: plain stores to private copy. MODE 0: atomic fallback into fin at ws[0].
template<int MODE>
__global__ __launch_bounds__(1024, 8)
void pl_k1(const float* __restrict__ logits, const int* __restrict__ y,
           const int* __restrict__ mask, const float* __restrict__ x_raw,
           const int* __restrict__ widx, const float* __restrict__ cw,
           float* __restrict__ ws, int n)
{
    __shared__ float lds[SEGW + NHIST];   // 77824 B -> 2 blocks/CU (32 waves)
    __shared__ float ce[2][16];
    const int tid = threadIdx.x;
    for (int s = tid; s < SEGW + NHIST; s += 1024) lds[s] = 0.0f;
    __syncthreads();

    const float cw0 = cw[0], cw1 = cw[1];
    float awn = 0.0f, aw = 0.0f;

    const int  lane   = tid & 63;
    const int  gwave  = blockIdx.x * 16 + (tid >> 6);
    const int  nwaves = gridDim.x * 16;
    const int  ngrp   = (n + 63) >> 6;      // 64-row groups
    const long nf4    = 2L * (long)n;       // total float4s in x_raw (8 words/row)
    const float4* x4p = (const float4*)x_raw;

    // shuffle sources: row r(=lane) needs f4 #2r (cols0-3: .z=col2,.w=col3) and f4 #(2r+1) (.x=col4).
    // f4 #j is held in xA of lane j (j<64) or xB of lane j-64.
    const int  s0 = (2 * lane) & 63;
    const int  s1 = (2 * lane + 1) & 63;
    const bool lo = lane < 32;

    for (int g = gwave; g < ngrp; g += nwaves) {
        const int  R0  = g << 6;
        const int  row = R0 + lane;
        const long fb  = 2L * (long)R0;

        // ---- dense loads, all issued up front ----
        float4 xA = {0.f,0.f,0.f,0.f}, xB = {0.f,0.f,0.f,0.f};
        const long iA = fb + lane, iB = fb + 64 + lane;
        if (iA < nf4) xA = x4p[iA];           // wave: 1 KB contiguous
        if (iB < nf4) xB = x4p[iB];           // wave: next 1 KB contiguous
        float2 lg = {0.0f, 0.0f};
        int yy = 0, mk = 0, wi = -1;
        if (row < n) {
            lg = ((const float2*)logits)[row];  // dense 8B/lane
            yy = y[row]; mk = mask[row]; wi = widx[row];  // dense 4B/lane
        }

        // ---- shuffle transpose: bring my row's cols 2,3,4 to my lane ----
        float zA = __shfl(xA.z, s0, 64), zB = __shfl(xB.z, s0, 64);
        float wA = __shfl(xA.w, s0, 64), wB = __shfl(xB.w, s0, 64);
        float aA = __shfl(xA.x, s1, 64), aB = __shfl(xB.x, s1, 64);
        float dob = lo ? zA : zB;   // col 2
        float pr  = lo ? wA : wB;   // col 3
        float as  = lo ? aA : aB;   // col 4

        row_op(lg.x, lg.y, yy, mk, wi, dob, pr, as, cw0, cw1, lds, awn, aw);
    }

    for (int o = 32; o > 0; o >>= 1) {
        awn += __shfl_down(awn, o, 64);
        aw  += __shfl_down(aw,  o, 64);
    }
    if ((tid & 63) == 0) { ce[0][tid >> 6] = awn; ce[1][tid >> 6] = aw; }
    __syncthreads();

    if (MODE == 1) {
        float* cb = ws + (size_t)blockIdx.x * CWP;
        for (int s = tid; s < SEGW + NHIST; s += 1024) cb[s] = lds[s];
        if (tid < 16)      cb[CE_OFF + tid]      = ce[0][tid];
        else if (tid < 32) cb[CE_OFF + tid]      = ce[1][tid - 16];
    } else {
        for (int s = tid; s < SEGW + NHIST; s += 1024)
            if (lds[s] != 0.0f) unsafeAtomicAdd(&ws[s], lds[s]);
        if (tid < 16)      unsafeAtomicAdd(&ws[CE_OFF + tid], ce[0][tid]);
        else if (tid < 32) unsafeAtomicAdd(&ws[CE_OFF + tid], ce[1][tid - 16]);
    }
}

// ---------------- Kmid: reduce C private copies into fin ----------------
__global__ __launch_bounds__(256)
void pl_kmid(const float* __restrict__ ws, float* __restrict__ fin, int C)
{
    __shared__ float sRed[256];
    const int j   = threadIdx.x & 63;
    const int g   = threadIdx.x >> 6;
    const int idx = blockIdx.x * 64 + j;

    float a0 = 0.f, a1 = 0.f, a2 = 0.f, a3 = 0.f;
    if (idx < CW) {
        int c = g;
        for (; c + 12 < C; c += 16) {
            a0 += ws[(size_t)(c)      * CWP + idx];
            a1 += ws[(size_t)(c + 4)  * CWP + idx];
            a2 += ws[(size_t)(c + 8)  * CWP + idx];
            a3 += ws[(size_t)(c + 12) * CWP + idx];
        }
        for (; c < C; c += 4) a0 += ws[(size_t)c * CWP + idx];
    }
    sRed[threadIdx.x] = (a0 + a1) + (a2 + a3);
    __syncthreads();
    if (g == 0 && idx < CW)
        fin[idx] = (sRed[j] + sRed[64 + j]) + (sRed[128 + j] + sRed[192 + j]);
}

// ---------------- K2: quantile + parallel window scan + outputs ----------------
__global__ __launch_bounds__(1024)
void pl_k2(const float* __restrict__ fin, float* __restrict__ out)
{
    __shared__ float        sS[1024];
    __shared__ float        sM[1024];
    __shared__ unsigned int sC[1024];
    __shared__ float        sV[2];
    __shared__ float        sRed[3][16];

    const int tid = threadIdx.x;
    const float* hist = fin + SEGW;
    const int CHUNK = NHIST / 1024;   // 7 bins per thread

    unsigned int hv[CHUNK];
    unsigned int c = 0;
    const int base = tid * CHUNK;
    for (int j = 0; j < CHUNK; ++j) { hv[j] = (unsigned int)hist[base + j]; c += hv[j]; }
    sC[tid] = c;
    __syncthreads();
    for (int off = 1; off < 1024; off <<= 1) {
        unsigned int v = (tid >= off) ? sC[tid - off] : 0u;
        __syncthreads();
        sC[tid] += v;
        __syncthreads();
    }
    const unsigned int nv  = sC[1023];
    const unsigned int pre = sC[tid] - c;

    if (tid == 0) { sV[0] = 1.0f; sV[1] = 1.0f; }
    __syncthreads();

    float nvf  = (float)nv;
    float pos  = 0.75f * (nvf - 1.0f);
    float fpos = floorf(pos);
    long  lo_l = (long)fpos;
    long  hi_l = (long)ceilf(pos);
    long  nmax = (nv > 0) ? (long)nv - 1 : 0;
    lo_l = lo_l < 0 ? 0 : (lo_l > nmax ? nmax : lo_l);
    hi_l = hi_l < 0 ? 0 : (hi_l > nmax ? nmax : hi_l);
    float frac = pos - fpos;

    if (nv > 0) {
        unsigned int lo = (unsigned int)lo_l, hi = (unsigned int)hi_l;
        if (lo >= pre && lo < pre + c) {
            unsigned int acc = pre;
            for (int j = 0; j < CHUNK; ++j) {
                acc += hv[j];
                if (lo < acc) { sV[0] = ((float)(base + j) + 0.5f) * (1.0f / (float)NHIST); break; }
            }
        }
        if (hi >= pre && hi < pre + c) {
            unsigned int acc = pre;
            for (int j = 0; j < CHUNK; ++j) {
                acc += hv[j];
                if (hi < acc) { sV[1] = ((float)(base + j) + 0.5f) * (1.0f / (float)NHIST); break; }
            }
        }
    }
    __syncthreads();
    float ref      = sV[0] * (1.0f - frac) + sV[1] * frac;
    float ref_dobs = fmaxf(ref, 1e-6f);
    float inv_ref  = 1.0f / ref_dobs;

    const float* f_sp  = fin;
    const float* f_spr = fin + NWIN;
    const float* f_spd = fin + 2 * NWIN;

    float va[4], vsp[4], vspr[4], vspd[4];
    bool  vinc[4];
    float S = 0.0f, M = -3.0e38f;
    const int w0 = tid * 4;
    for (int j = 0; j < 4; ++j) {
        int   wdx = w0 + j;
        float sp  = f_sp[wdx];
        float spr = f_spr[wdx];
        float spd = f_spd[wdx];
        float a   = spr * DELTA_T_F - SERVICE;
        bool  inc = (sp >= 1e-8f);   // == (cnt>=1 && sp>=1e-8)
        va[j] = a; vsp[j] = sp; vspr[j] = spr; vspd[j] = spd; vinc[j] = inc;
        if (inc) { M = fmaxf(M + a, 0.0f); S = S + a; }
    }
    sS[tid] = S; sM[tid] = M;
    __syncthreads();
    for (int off = 1; off < 1024; off <<= 1) {
        float vs = 0.0f, vm = -3.0e38f;
        if (tid >= off) { vs = sS[tid - off]; vm = sM[tid - off]; }
        __syncthreads();
        if (tid >= off) {
            float s2 = sS[tid], m2 = sM[tid];
            sS[tid] = vs + s2;
            sM[tid] = fmaxf(vm + s2, m2);
        }
        __syncthreads();
    }
    float q = 0.0f;
    if (tid > 0) q = fmaxf(sS[tid - 1], sM[tid - 1]);

    float fsum = 0.0f, lsum = 0.0f, isum = 0.0f;
    for (int j = 0; j < 4; ++j) {
        float qn    = fmaxf(q + va[j], 0.0f);
        float dmean = vspd[j] / (vsp[j] + 1e-6f);
        float dsc   = dmean * inv_ref;
        float oq    = fmaxf(dsc - 1.0f, 0.0f) * SERVICE;
        float fw    = (qn - oq) / (SERVICE + 1e-6f);
        fw = fw * fw;
        float rho = vspr[j] / (CAPACITY_F + 1e-6f);
        rho = fminf(fmaxf(rho, 0.0f), 0.995f);
        float dth = 1.0f / (1.0f - rho + 1e-6f);
        float lt  = fmaxf(dth - dsc, 0.0f);
        if (vinc[j]) { fsum += fw; lsum += lt; isum += 1.0f; q = qn; }
    }

    for (int o = 32; o > 0; o >>= 1) {
        fsum += __shfl_down(fsum, o, 64);
        lsum += __shfl_down(lsum, o, 64);
        isum += __shfl_down(isum, o, 64);
    }
    const int wv = tid >> 6;
    if ((tid & 63) == 0) { sRed[0][wv] = fsum; sRed[1][wv] = lsum; sRed[2][wv] = isum; }
    __syncthreads();
    if (tid == 0) {
        float F = 0.0f, L = 0.0f, I = 0.0f;
        float A = 0.0f, B = 0.0f;
        for (int k = 0; k < 16; ++k) {
            F += sRed[0][k]; L += sRed[1][k]; I += sRed[2][k];
            A += fin[CE_OFF + k]; B += fin[CE_OFF + 16 + k];
        }
        float l_data = A / B;
        float l_flow = (I > 0.0f) ? F / fmaxf(I, 1.0f) : 0.0f;
        float l_lat  = (I > 0.0f) ? L / fmaxf(I, 1.0f) : 0.0f;
        out[0] = l_data + 0.1f * l_flow + 0.1f * l_lat;
        out[1] = l_data;
        out[2] = l_flow;
        out[3] = l_lat;
    }
}

extern "C" void kernel_launch(void* const* d_in, const int* in_sizes, int n_in,
                              void* d_out, int out_size, void* d_ws, size_t ws_size,
                              hipStream_t stream) {
    const float* logits = (const float*)d_in[0];
    const int*   y      = (const int*)d_in[1];
    const int*   mask   = (const int*)d_in[2];
    const float* x_raw  = (const float*)d_in[3];
    const int*   widx   = (const int*)d_in[4];
    const float* cw     = (const float*)d_in[5];
    float* out = (float*)d_out;
    int n = in_sizes[1];   // N from y

    float* ws = (float*)d_ws;
    size_t words = ws_size / 4;
    long   cap   = (words > CW) ? (long)((words - CW) / CWP) : 0;
    int    nblk  = (cap > MAXBLK) ? MAXBLK : (int)cap;

    if (nblk >= 64) {
        float* fin = ws + (size_t)nblk * CWP;
        hipLaunchKernelGGL((pl_k1<1>), dim3(nblk), dim3(1024), 0, stream,
                           logits, y, mask, x_raw, widx, cw, ws, n);
        hipLaunchKernelGGL(pl_kmid, dim3((CW + 63) / 64), dim3(256), 0, stream,
                           ws, fin, nblk);
        hipLaunchKernelGGL(pl_k2, dim3(1), dim3(1024), 0, stream,
                           fin, out);
    } else {
        hipMemsetAsync(d_ws, 0, (size_t)CW * 4, stream);
        hipLaunchKernelGGL((pl_k1<0>), dim3(512), dim3(1024), 0, stream,
                           logits, y, mask, x_raw, widx, cw, ws, n);
        hipLaunchKernelGGL(pl_k2, dim3(1), dim3(1024), 0, stream,
                           ws, out);
    }
}

// Round 7
// 274.159 us; speedup vs baseline: 1.0815x; 1.0346x over previous
//
#include <hip/hip_runtime.h>
#include <math.h>

#define NWIN  4096
#define NHIST 6144                  // 6*1024; float bins (counts exact < 2^24)
// bank-skewed replica layout (words):
#define SP_OFF   0                  // sum_p  [0,4096)
#define SPR_OFF  4097               // sum_pr [4097,8193)   bank +1
#define SPD_OFF  8194               // sum_pd [8194,12290)  bank +2
#define HIST_OFF 12292              // hist   [12292,18436)
#define RWORDS   18436              // logical words per replica
#define REP      18464              // replica stride (pad)
#define CE_OFF   RWORDS             // in the flushed copy: 16 wnll + 16 w
#define CW       (RWORDS + 32)      // 18468 words per flushed copy
#define CWP      18496              // padded stride (73984 B)
#define MAXBLK   256

#define SERVICE    1.0e8f   // CAPACITY * DELTA_T
#define CAPACITY_F 1.0e9f
#define DELTA_T_F  0.1f

// per-row work
__device__ __forceinline__
void row_op(float l0, float l1, int yy, int mk, int wi,
            float dob_raw, float pr_raw, float as_raw,
            float cw0, float cw1, float* L, float& awn, float& aw)
{
    float d = l0 - l1;
    float e = __expf(d);
    float t = __logf(1.0f + e);
    float nll = yy ? t : (t - d);
    float w   = (yy ? cw1 : cw0) * (mk ? 1.0f : 0.0f);
    awn += w * nll;
    aw  += w;
    if (mk && wi >= 0) {
        float p   = 1.0f / (1.0f + e);
        int   seg = (wi < NWIN) ? wi : (NWIN - 1);
        float dob = fmaxf(dob_raw, 0.0f);
        float pr  = fmaxf(pr_raw,  0.0f);
        float as  = fmaxf(as_raw,  0.0f) * 1000.0f;
        // 3 adds hit banks b, b+1, b+2 (skewed offsets) — no intra-row same-bank serialize
        unsafeAtomicAdd(&L[SP_OFF  + seg], p);
        unsafeAtomicAdd(&L[SPR_OFF + seg], p * (pr * as));
        unsafeAtomicAdd(&L[SPD_OFF + seg], p * dob);
        int b = (int)(dob * (float)NHIST);
        b = (b < NHIST - 1) ? b : (NHIST - 1);
        b = (b > 0) ? b : 0;
        unsafeAtomicAdd(&L[HIST_OFF + b], 1.0f);
    }
}

// ---------------- K1: grid-stride row pass; 2 LDS accumulator replicas per block ----------------
// MODE 1: plain stores of (replica0+replica1) to private copy. MODE 0: atomic fallback into ws[0].
template<int MODE>
__global__ __launch_bounds__(1024)
void pl_k1(const float* __restrict__ logits, const int* __restrict__ y,
           const int* __restrict__ mask, const float* __restrict__ x_raw,
           const int* __restrict__ widx, const float* __restrict__ cw,
           float* __restrict__ ws, int n)
{
    __shared__ float lds[2 * REP];      // 147,712 B -> 1 block/CU (16 waves)
    __shared__ float ce[2][16];
    const int tid = threadIdx.x;
    for (int s = tid; s < 2 * REP; s += 1024) lds[s] = 0.0f;
    __syncthreads();

    const float cw0 = cw[0], cw1 = cw[1];
    float awn = 0.0f, aw = 0.0f;

    float* L = lds + (tid >> 9) * REP;  // waves 0-7 -> replica 0, waves 8-15 -> replica 1

    const int stride = gridDim.x * 1024;
    for (int i = blockIdx.x * 1024 + tid; i < n; i += stride) {
        float2 lg  = ((const float2*)logits)[i];
        int    yy  = y[i];
        int    mk  = mask[i];
        int    wi  = widx[i];
        float2 x23 = *(const float2*)(x_raw + 8 * (size_t)i + 2); // cols 2,3
        float  x4  = x_raw[8 * (size_t)i + 4];                    // col 4
        row_op(lg.x, lg.y, yy, mk, wi, x23.x, x23.y, x4, cw0, cw1, L, awn, aw);
    }

    for (int o = 32; o > 0; o >>= 1) {
        awn += __shfl_down(awn, o, 64);
        aw  += __shfl_down(aw,  o, 64);
    }
    if ((tid & 63) == 0) { ce[0][tid >> 6] = awn; ce[1][tid >> 6] = aw; }
    __syncthreads();

    if (MODE == 1) {
        float* cb = ws + (size_t)blockIdx.x * CWP;
        for (int s = tid; s < RWORDS; s += 1024) cb[s] = lds[s] + lds[REP + s];
        if (tid < 16)      cb[CE_OFF + tid]      = ce[0][tid];
        else if (tid < 32) cb[CE_OFF + tid]      = ce[1][tid - 16];
    } else {
        for (int s = tid; s < RWORDS; s += 1024) {
            float v = lds[s] + lds[REP + s];
            if (v != 0.0f) unsafeAtomicAdd(&ws[s], v);
        }
        if (tid < 16)      unsafeAtomicAdd(&ws[CE_OFF + tid], ce[0][tid]);
        else if (tid < 32) unsafeAtomicAdd(&ws[CE_OFF + tid], ce[1][tid - 16]);
    }
}

// ---------------- Kmid: reduce C private copies into fin ----------------
__global__ __launch_bounds__(256)
void pl_kmid(const float* __restrict__ ws, float* __restrict__ fin, int C)
{
    __shared__ float sRed[256];
    const int j   = threadIdx.x & 63;
    const int g   = threadIdx.x >> 6;
    const int idx = blockIdx.x * 64 + j;

    float a0 = 0.f, a1 = 0.f, a2 = 0.f, a3 = 0.f;
    if (idx < CW) {
        int c = g;
        for (; c + 12 < C; c += 16) {
            a0 += ws[(size_t)(c)      * CWP + idx];
            a1 += ws[(size_t)(c + 4)  * CWP + idx];
            a2 += ws[(size_t)(c + 8)  * CWP + idx];
            a3 += ws[(size_t)(c + 12) * CWP + idx];
        }
        for (; c < C; c += 4) a0 += ws[(size_t)c * CWP + idx];
    }
    sRed[threadIdx.x] = (a0 + a1) + (a2 + a3);
    __syncthreads();
    if (g == 0 && idx < CW)
        fin[idx] = (sRed[j] + sRed[64 + j]) + (sRed[128 + j] + sRed[192 + j]);
}

// ---------------- K2: quantile + parallel window scan + outputs ----------------
__global__ __launch_bounds__(1024)
void pl_k2(const float* __restrict__ fin, float* __restrict__ out)
{
    __shared__ float        sS[1024];
    __shared__ float        sM[1024];
    __shared__ unsigned int sC[1024];
    __shared__ float        sV[2];
    __shared__ float        sRed[3][16];

    const int tid = threadIdx.x;
    const float* hist = fin + HIST_OFF;
    const int CHUNK = NHIST / 1024;   // 6 bins per thread

    unsigned int hv[CHUNK];
    unsigned int c = 0;
    const int base = tid * CHUNK;
    for (int j = 0; j < CHUNK; ++j) { hv[j] = (unsigned int)hist[base + j]; c += hv[j]; }
    sC[tid] = c;
    __syncthreads();
    for (int off = 1; off < 1024; off <<= 1) {
        unsigned int v = (tid >= off) ? sC[tid - off] : 0u;
        __syncthreads();
        sC[tid] += v;
        __syncthreads();
    }
    const unsigned int nv  = sC[1023];
    const unsigned int pre = sC[tid] - c;

    if (tid == 0) { sV[0] = 1.0f; sV[1] = 1.0f; }
    __syncthreads();

    float nvf  = (float)nv;
    float pos  = 0.75f * (nvf - 1.0f);
    float fpos = floorf(pos);
    long  lo_l = (long)fpos;
    long  hi_l = (long)ceilf(pos);
    long  nmax = (nv > 0) ? (long)nv - 1 : 0;
    lo_l = lo_l < 0 ? 0 : (lo_l > nmax ? nmax : lo_l);
    hi_l = hi_l < 0 ? 0 : (hi_l > nmax ? nmax : hi_l);
    float frac = pos - fpos;

    if (nv > 0) {
        unsigned int lo = (unsigned int)lo_l, hi = (unsigned int)hi_l;
        if (lo >= pre && lo < pre + c) {
            unsigned int acc = pre;
            for (int j = 0; j < CHUNK; ++j) {
                acc += hv[j];
                if (lo < acc) { sV[0] = ((float)(base + j) + 0.5f) * (1.0f / (float)NHIST); break; }
            }
        }
        if (hi >= pre && hi < pre + c) {
            unsigned int acc = pre;
            for (int j = 0; j < CHUNK; ++j) {
                acc += hv[j];
                if (hi < acc) { sV[1] = ((float)(base + j) + 0.5f) * (1.0f / (float)NHIST); break; }
            }
        }
    }
    __syncthreads();
    float ref      = sV[0] * (1.0f - frac) + sV[1] * frac;
    float ref_dobs = fmaxf(ref, 1e-6f);
    float inv_ref  = 1.0f / ref_dobs;

    const float* f_sp  = fin + SP_OFF;
    const float* f_spr = fin + SPR_OFF;
    const float* f_spd = fin + SPD_OFF;

    float va[4], vsp[4], vspr[4], vspd[4];
    bool  vinc[4];
    float S = 0.0f, M = -3.0e38f;
    const int w0 = tid * 4;
    for (int j = 0; j < 4; ++j) {
        int   wdx = w0 + j;
        float sp  = f_sp[wdx];
        float spr = f_spr[wdx];
        float spd = f_spd[wdx];
        float a   = spr * DELTA_T_F - SERVICE;
        bool  inc = (sp >= 1e-8f);   // == (cnt>=1 && sp>=1e-8)
        va[j] = a; vsp[j] = sp; vspr[j] = spr; vspd[j] = spd; vinc[j] = inc;
        if (inc) { M = fmaxf(M + a, 0.0f); S = S + a; }
    }
    sS[tid] = S; sM[tid] = M;
    __syncthreads();
    for (int off = 1; off < 1024; off <<= 1) {
        float vs = 0.0f, vm = -3.0e38f;
        if (tid >= off) { vs = sS[tid - off]; vm = sM[tid - off]; }
        __syncthreads();
        if (tid >= off) {
            float s2 = sS[tid], m2 = sM[tid];
            sS[tid] = vs + s2;
            sM[tid] = fmaxf(vm + s2, m2);
        }
        __syncthreads();
    }
    float q = 0.0f;
    if (tid > 0) q = fmaxf(sS[tid - 1], sM[tid - 1]);

    float fsum = 0.0f, lsum = 0.0f, isum = 0.0f;
    for (int j = 0; j < 4; ++j) {
        float qn    = fmaxf(q + va[j], 0.0f);
        float dmean = vspd[j] / (vsp[j] + 1e-6f);
        float dsc   = dmean * inv_ref;
        float oq    = fmaxf(dsc - 1.0f, 0.0f) * SERVICE;
        float fw    = (qn - oq) / (SERVICE + 1e-6f);
        fw = fw * fw;
        float rho = vspr[j] / (CAPACITY_F + 1e-6f);
        rho = fminf(fmaxf(rho, 0.0f), 0.995f);
        float dth = 1.0f / (1.0f - rho + 1e-6f);
        float lt  = fmaxf(dth - dsc, 0.0f);
        if (vinc[j]) { fsum += fw; lsum += lt; isum += 1.0f; q = qn; }
    }

    for (int o = 32; o > 0; o >>= 1) {
        fsum += __shfl_down(fsum, o, 64);
        lsum += __shfl_down(lsum, o, 64);
        isum += __shfl_down(isum, o, 64);
    }
    const int wv = tid >> 6;
    if ((tid & 63) == 0) { sRed[0][wv] = fsum; sRed[1][wv] = lsum; sRed[2][wv] = isum; }
    __syncthreads();
    if (tid == 0) {
        float F = 0.0f, L = 0.0f, I = 0.0f;
        float A = 0.0f, B = 0.0f;
        for (int k = 0; k < 16; ++k) {
            F += sRed[0][k]; L += sRed[1][k]; I += sRed[2][k];
            A += fin[CE_OFF + k]; B += fin[CE_OFF + 16 + k];
        }
        float l_data = A / B;
        float l_flow = (I > 0.0f) ? F / fmaxf(I, 1.0f) : 0.0f;
        float l_lat  = (I > 0.0f) ? L / fmaxf(I, 1.0f) : 0.0f;
        out[0] = l_data + 0.1f * l_flow + 0.1f * l_lat;
        out[1] = l_data;
        out[2] = l_flow;
        out[3] = l_lat;
    }
}

extern "C" void kernel_launch(void* const* d_in, const int* in_sizes, int n_in,
                              void* d_out, int out_size, void* d_ws, size_t ws_size,
                              hipStream_t stream) {
    const float* logits = (const float*)d_in[0];
    const int*   y      = (const int*)d_in[1];
    const int*   mask   = (const int*)d_in[2];
    const float* x_raw  = (const float*)d_in[3];
    const int*   widx   = (const int*)d_in[4];
    const float* cw     = (const float*)d_in[5];
    float* out = (float*)d_out;
    int n = in_sizes[1];   // N from y

    float* ws = (float*)d_ws;
    size_t words = ws_size / 4;
    long   cap   = (words > CW) ? (long)((words - CW) / CWP) : 0;
    int    nblk  = (cap > MAXBLK) ? MAXBLK : (int)cap;

    if (nblk >= 64) {
        float* fin = ws + (size_t)nblk * CWP;
        hipLaunchKernelGGL((pl_k1<1>), dim3(nblk), dim3(1024), 0, stream,
                           logits, y, mask, x_raw, widx, cw, ws, n);
        hipLaunchKernelGGL(pl_kmid, dim3((CW + 63) / 64), dim3(256), 0, stream,
                           ws, fin, nblk);
        hipLaunchKernelGGL(pl_k2, dim3(1), dim3(1024), 0, stream,
                           fin, out);
    } else {
        hipMemsetAsync(d_ws, 0, (size_t)CW * 4, stream);
        hipLaunchKernelGGL((pl_k1<0>), dim3(256), dim3(1024), 0, stream,
                           logits, y, mask, x_raw, widx, cw, ws, n);
        hipLaunchKernelGGL(pl_k2, dim3(1), dim3(1024), 0, stream,
                           ws, out);
    }
}